// Round 2
// baseline (196.038 us; speedup 1.0000x reference)
//
#include <hip/hip_runtime.h>

// SaltAndPepper: out = where(mask==0, 0, where(mask==1, 1, image))
// image: (32,3,512,512) f32, mask: (32,1,512,512) i32 broadcast over C.
// Memory-bound streaming op. Structure: one thread per float4 of OUTPUT,
// purely linear addressing (1 int4 + 1 float4 load, 1 float4 store per
// thread). Mask re-read per channel is absorbed by L2/L3 (32 MiB mask).

constexpr int B  = 32;
constexpr int C  = 3;
constexpr int HW = 512 * 512;              // 262144 pixels per plane
constexpr int G_PER_PLANE = HW / 4;        // 65536 float4 groups (2^16)
constexpr int TOTAL_G = B * C * G_PER_PLANE;  // 6,291,456

__global__ __launch_bounds__(256)
void sp_kernel(const float* __restrict__ img,
               const int*   __restrict__ mask,
               float*       __restrict__ out) {
    const int t = blockIdx.x * blockDim.x + threadIdx.x;  // one per out float4
    if (t >= TOTAL_G) return;

    const int plane = t >> 16;        // b*C + c, in [0, 96)
    const int b     = plane / 3;      // compiler: magic-mul, cheap
    const int g     = t & (G_PER_PLANE - 1);

    const int4 m = *(const int4*)(mask + (size_t)b * HW + (size_t)g * 4);

    const size_t off = (size_t)t * 4;   // linear over image/out
    const float4 v = *(const float4*)(img + off);

    float4 r;
    r.x = (m.x == 0) ? 0.0f : ((m.x == 1) ? 1.0f : v.x);
    r.y = (m.y == 0) ? 0.0f : ((m.y == 1) ? 1.0f : v.y);
    r.z = (m.z == 0) ? 0.0f : ((m.z == 1) ? 1.0f : v.z);
    r.w = (m.w == 0) ? 0.0f : ((m.w == 1) ? 1.0f : v.w);
    *(float4*)(out + off) = r;
}

extern "C" void kernel_launch(void* const* d_in, const int* in_sizes, int n_in,
                              void* d_out, int out_size, void* d_ws, size_t ws_size,
                              hipStream_t stream) {
    const float* img  = (const float*)d_in[0];
    const int*   mask = (const int*)d_in[1];
    float*       out  = (float*)d_out;

    const int block = 256;
    const int grid  = TOTAL_G / block;   // 24576 blocks, exact
    sp_kernel<<<grid, block, 0, stream>>>(img, mask, out);
}